// Round 4
// baseline (415.529 us; speedup 1.0000x reference)
//
#include <hip/hip_runtime.h>
#include <hip/hip_bf16.h>
#include <cstdint>

// ---------------------------------------------------------------------------
// MLPDecoder: logit[e] = relu([zu, zv, |zu-zv|] @ W1 + b1) @ W2 + b2
//   z: [100000,128] f32, edge_index: [2,E] int, W1: [384,128], b1:[128],
//   W2: [128,1], b2:[1].  Output: [E] f32.
//
// R4 = R3 with the launch-bounds spill fixed.
//   R3's __launch_bounds__(512,2) was interpreted as min 2 BLOCKS/CU ->
//   VGPR cap 128 -> ~190MB scratch writes (WRITE_SIZE counter), decode 310us.
//   (512,1) -> cap 256; live set ~160-200 regs fits with zero spill.
//  - 256 persistent blocks x 512 threads (1 block/CU, 8 waves = 2/SIMD).
//  - Packed W1 (96KB) resident in LDS; B-frags via ds_read_b128.
//  - Wave = 32 edges x full 128 cols; no cross-wave reduce; the only
//    __syncthreads is after the one-time W1 staging.
//  - K-loop in c-groups (ks = c, 4+c, 8+c): after group c, zu/zv chunk c is
//    dead and the NEXT tile's chunk-c gather overwrites it IN PLACE
//    (uniform ~3/4-K-loop prefetch distance for every chunk).
// ---------------------------------------------------------------------------

typedef __bf16 bf16_t;
typedef __bf16 bf16x8 __attribute__((ext_vector_type(8)));
typedef float  floatx4 __attribute__((ext_vector_type(4)));

#define DIM 128
#define E_TILE 256          // edges per block-tile (8 waves x 32 edges)
#define N_KSTEP 12          // 384 / 32
#define N_NTILE 8           // 128 / 16
#define GRID_B 256          // persistent blocks (1 per CU)

// --- cast z fp32 -> bf16 ----------------------------------------------------
__global__ void cast_z_kernel(const float* __restrict__ z, bf16_t* __restrict__ zb, int n) {
    int idx = (blockIdx.x * 256 + threadIdx.x) * 8;
    if (idx + 8 > n) return;
    const float4* src = reinterpret_cast<const float4*>(z + idx);
    float4 a = src[0], b = src[1];
    bf16x8 o;
    o[0] = (bf16_t)a.x; o[1] = (bf16_t)a.y; o[2] = (bf16_t)a.z; o[3] = (bf16_t)a.w;
    o[4] = (bf16_t)b.x; o[5] = (bf16_t)b.y; o[6] = (bf16_t)b.z; o[7] = (bf16_t)b.w;
    *reinterpret_cast<bf16x8*>(zb + idx) = o;
}

// --- pack W1 [384,128] f32 row-major -> MFMA B-fragment order bf16 ----------
// frag index f = (kstep*8 + ntile); element j of lane l:
//   B[k = kstep*32 + (l>>4)*8 + j][n = ntile*16 + (l&15)]
// stored lane-contiguous: Wp[f*64 + lane] is a 16B bf16x8.
__global__ void pack_w1_kernel(const float* __restrict__ W1, bf16_t* __restrict__ Wp) {
    int f = blockIdx.x * 256 + threadIdx.x;     // 0 .. 12*8*64-1
    if (f >= N_KSTEP * N_NTILE * 64) return;
    int lane = f & 63;
    int nt   = (f >> 6) & 7;
    int ks   = f >> 9;
    int n  = nt * 16 + (lane & 15);
    int k0 = ks * 32 + (lane >> 4) * 8;
    bf16x8 o;
#pragma unroll
    for (int j = 0; j < 8; ++j) o[j] = (bf16_t)W1[(k0 + j) * DIM + n];
    reinterpret_cast<bf16x8*>(Wp)[f] = o;
}

// --- main fused kernel ------------------------------------------------------
template <bool PRECAST>
__global__ __launch_bounds__(512, 1)
void decode_kernel(const void* __restrict__ zsrc,
                   const int* __restrict__ ei,       // [2*E]
                   const bf16_t* __restrict__ Wp,    // packed W1 (96KB)
                   const float* __restrict__ b1,
                   const float* __restrict__ W2,
                   const float* __restrict__ b2,
                   float* __restrict__ out, int E) {
    __shared__ __align__(16) bf16_t Bsm[N_KSTEP * N_NTILE * 64 * 8];  // 96 KiB

    const int tid = threadIdx.x;

    // ---- stage packed W1 into LDS, once per persistent block ----
    {
        const uint4* src = reinterpret_cast<const uint4*>(Wp);
        uint4* dst = reinterpret_cast<uint4*>(Bsm);
#pragma unroll
        for (int i = 0; i < 12; ++i)            // 12 * 512 * 16B = 96 KiB
            dst[i * 512 + tid] = src[i * 512 + tid];
    }
    __syncthreads();    // the only block-wide barrier in the kernel

    const int wave = tid >> 6, lane = tid & 63;
    const int l15 = lane & 15, quad = lane >> 4;

    // ---- epilogue params (full n range per wave) ----
    float b1v[8], w2v[8];
#pragma unroll
    for (int nt = 0; nt < 8; ++nt) {
        int n = nt * 16 + l15;
        b1v[nt] = b1[n];
        w2v[nt] = W2[n];
    }
    const float bias2 = b2[0];

    const int ntiles = (E + E_TILE - 1) / E_TILE;

    // gather one 16B chunk of zu/zv for (mt, c): cols [c*32+quad*8, +8)
    auto gatherChunk = [&](bf16x8& du, bf16x8& dv, int nu, int nv, int c) {
        if (PRECAST) {
            const bf16_t* zb = (const bf16_t*)zsrc;
            du = *reinterpret_cast<const bf16x8*>(zb + (size_t)nu * DIM + c * 32 + quad * 8);
            dv = *reinterpret_cast<const bf16x8*>(zb + (size_t)nv * DIM + c * 32 + quad * 8);
        } else {
            const float* zf = (const float*)zsrc;
            const float4* pu = reinterpret_cast<const float4*>(zf + (size_t)nu * DIM + c * 32 + quad * 8);
            const float4* pv = reinterpret_cast<const float4*>(zf + (size_t)nv * DIM + c * 32 + quad * 8);
            float4 a = pu[0], b = pu[1];
            bf16x8 o;
            o[0] = (bf16_t)a.x; o[1] = (bf16_t)a.y; o[2] = (bf16_t)a.z; o[3] = (bf16_t)a.w;
            o[4] = (bf16_t)b.x; o[5] = (bf16_t)b.y; o[6] = (bf16_t)b.z; o[7] = (bf16_t)b.w;
            du = o;
            a = pv[0]; b = pv[1];
            o[0] = (bf16_t)a.x; o[1] = (bf16_t)a.y; o[2] = (bf16_t)a.z; o[3] = (bf16_t)a.w;
            o[4] = (bf16_t)b.x; o[5] = (bf16_t)b.y; o[6] = (bf16_t)b.z; o[7] = (bf16_t)b.w;
            dv = o;
        }
    };

    auto loadIdx = [&](int t, int mt, int& nu, int& nv) {
        int e = t * E_TILE + wave * 32 + mt * 16 + l15;
        if (e >= E) e = E - 1;                   // clamp: harmless duplicate work
        nu = ei[e];
        nv = ei[E + e];
    };

    auto loadB = [&](bf16x8* dst, int ks) {
#pragma unroll
        for (int nt = 0; nt < 8; ++nt)
            dst[nt] = *reinterpret_cast<const bf16x8*>(
                &Bsm[(size_t)((ks * N_NTILE + nt) * 64 + lane) * 8]);
    };

    // ---- single A state; prologue: fully gather tile blockIdx.x ----
    bf16x8 uz[2][4], vz[2][4];
    {
        int nu[2], nv[2];
#pragma unroll
        for (int mt = 0; mt < 2; ++mt) loadIdx(blockIdx.x, mt, nu[mt], nv[mt]);
#pragma unroll
        for (int mt = 0; mt < 2; ++mt)
#pragma unroll
            for (int c = 0; c < 4; ++c)
                gatherChunk(uz[mt][c], vz[mt][c], nu[mt], nv[mt], c);
    }

    // ---- persistent grid-stride loop ----
    for (int t = blockIdx.x; t < ntiles; t += GRID_B) {
        // next tile's node indices (prefetch target); clamped if past the end
        int nnu[2], nnv[2];
#pragma unroll
        for (int mt = 0; mt < 2; ++mt) loadIdx(t + GRID_B, mt, nnu[mt], nnv[mt]);

        floatx4 acc[2][8];
#pragma unroll
        for (int mt = 0; mt < 2; ++mt)
#pragma unroll
            for (int nt = 0; nt < 8; ++nt) acc[mt][nt] = (floatx4)0.0f;

        // K-loop: 4 c-groups of (ks=c, 4+c, 8+c). After group c, chunk c of
        // uz/vz is dead -> overwrite in place with next tile's gather.
#pragma unroll
        for (int c = 0; c < 4; ++c) {
            {   // ks = c : A = zu chunk c
                bf16x8 bc[8];
                loadB(bc, c);
#pragma unroll
                for (int mt = 0; mt < 2; ++mt)
#pragma unroll
                    for (int nt = 0; nt < 8; ++nt)
                        acc[mt][nt] = __builtin_amdgcn_mfma_f32_16x16x32_bf16(
                            uz[mt][c], bc[nt], acc[mt][nt], 0, 0, 0);
            }
            {   // ks = 4+c : A = zv chunk c
                bf16x8 bc[8];
                loadB(bc, 4 + c);
#pragma unroll
                for (int mt = 0; mt < 2; ++mt)
#pragma unroll
                    for (int nt = 0; nt < 8; ++nt)
                        acc[mt][nt] = __builtin_amdgcn_mfma_f32_16x16x32_bf16(
                            vz[mt][c], bc[nt], acc[mt][nt], 0, 0, 0);
            }
            {   // ks = 8+c : A = |zu - zv| chunk c
                bf16x8 bc[8];
                loadB(bc, 8 + c);
#pragma unroll
                for (int mt = 0; mt < 2; ++mt) {
                    bf16x8 u = uz[mt][c], v = vz[mt][c];
                    bf16x8 d;
#pragma unroll
                    for (int j = 0; j < 8; ++j)
                        d[j] = (bf16_t)fabsf((float)u[j] - (float)v[j]);
#pragma unroll
                    for (int nt = 0; nt < 8; ++nt)
                        acc[mt][nt] = __builtin_amdgcn_mfma_f32_16x16x32_bf16(
                            d, bc[nt], acc[mt][nt], 0, 0, 0);
                }
            }
            // chunk c dead: gather next tile's chunk c into the same registers
#pragma unroll
            for (int mt = 0; mt < 2; ++mt)
                gatherChunk(uz[mt][c], vz[mt][c], nnu[mt], nnv[mt], c);
        }

        // ---- epilogue: bias + relu + dot(W2), in-wave butterfly over n ----
        // C/D layout: n = nt*16 + l15, m = quad*4 + r
#pragma unroll
        for (int mt = 0; mt < 2; ++mt)
#pragma unroll
            for (int r = 0; r < 4; ++r) {
                float s = 0.f;
#pragma unroll
                for (int nt = 0; nt < 8; ++nt) {
                    float h = acc[mt][nt][r] + b1v[nt];
                    h = fmaxf(h, 0.f);
                    s += h * w2v[nt];
                }
                s += __shfl_xor(s, 1);
                s += __shfl_xor(s, 2);
                s += __shfl_xor(s, 4);
                s += __shfl_xor(s, 8);
                if (l15 == 0) {
                    int e = t * E_TILE + wave * 32 + mt * 16 + quad * 4 + r;
                    if (e < E) out[e] = s + bias2;
                }
            }
    }
}

// ---------------------------------------------------------------------------
extern "C" void kernel_launch(void* const* d_in, const int* in_sizes, int n_in,
                              void* d_out, int out_size, void* d_ws, size_t ws_size,
                              hipStream_t stream) {
    const float* z  = (const float*)d_in[0];
    const int*   ei = (const int*)d_in[1];
    const float* W1 = (const float*)d_in[2];
    const float* b1 = (const float*)d_in[3];
    const float* W2 = (const float*)d_in[4];
    const float* b2 = (const float*)d_in[5];
    float* out = (float*)d_out;

    const int E  = in_sizes[1] / 2;
    const int zn = in_sizes[0];

    const size_t zb_bytes = (size_t)zn * sizeof(bf16_t);
    const size_t wp_bytes = (size_t)N_KSTEP * N_NTILE * 64 * 16;  // 98304
    const bool precast = ws_size >= zb_bytes + wp_bytes;

    bf16_t* zb = (bf16_t*)d_ws;
    bf16_t* wp = precast ? (bf16_t*)((char*)d_ws + zb_bytes) : (bf16_t*)d_ws;

    hipLaunchKernelGGL(pack_w1_kernel, dim3((N_KSTEP * N_NTILE * 64 + 255) / 256),
                       dim3(256), 0, stream, W1, wp);

    if (precast) {
        hipLaunchKernelGGL(cast_z_kernel, dim3((zn / 8 + 255) / 256), dim3(256),
                           0, stream, z, zb, zn);
        hipLaunchKernelGGL((decode_kernel<true>), dim3(GRID_B), dim3(512), 0,
                           stream, (const void*)zb, ei, wp, b1, W2, b2, out, E);
    } else {
        hipLaunchKernelGGL((decode_kernel<false>), dim3(GRID_B), dim3(512), 0,
                           stream, (const void*)z, ei, wp, b1, W2, b2, out, E);
    }
}

// Round 6
// 397.122 us; speedup vs baseline: 1.0463x; 1.0463x over previous
//
#include <hip/hip_runtime.h>
#include <hip/hip_bf16.h>
#include <cstdint>

// ---------------------------------------------------------------------------
// MLPDecoder: logit[e] = relu([zu, zv, |zu-zv|] @ W1 + b1) @ W2 + b2
//   z: [100000,128] f32, edge_index: [2,E] int, W1: [384,128], b1:[128],
//   W2: [128,1], b2:[1].  Output: [E] f32.
//
// R6: fit the 128-arch/128-AGPR register split by streaming the A-state.
//   R3/R4 evidence: VGPR_Count=128 under BOTH (512,2) and (512,1) + 190MB
//   scratch writes => compiler splits the 256-reg/wave unified file at
//   accum_offset=128 and the ARCH side spilled (A-state 64 + bc 32 + params).
//   Fix: keep acc[2][8] (64 regs, MFMA C/D -> AGPR side) but hold only TWO
//   A-chunks (32 arch regs) in a ping-pong: compute c-group g while
//   prefetching chunk g+1 (or chunk 0 of the next tile at g=3).
//   Worst-case arch live ~100 < 128 -> no spill by construction.
//  - 256 persistent blocks x 512 threads (1 block/CU, 8 waves = 2/SIMD).
//  - Packed W1 (96KB) resident in LDS; B-frags via ds_read_b128 (4 at a time).
//  - Wave = 32 edges x full 128 cols; single __syncthreads after W1 staging.
// ---------------------------------------------------------------------------

typedef __bf16 bf16_t;
typedef __bf16 bf16x8 __attribute__((ext_vector_type(8)));
typedef float  floatx4 __attribute__((ext_vector_type(4)));

#define DIM 128
#define E_TILE 256          // edges per block-tile (8 waves x 32 edges)
#define N_KSTEP 12          // 384 / 32
#define N_NTILE 8           // 128 / 16
#define GRID_B 256          // persistent blocks (1 per CU)

// --- cast z fp32 -> bf16 ----------------------------------------------------
__global__ void cast_z_kernel(const float* __restrict__ z, bf16_t* __restrict__ zb, int n) {
    int idx = (blockIdx.x * 256 + threadIdx.x) * 8;
    if (idx + 8 > n) return;
    const float4* src = reinterpret_cast<const float4*>(z + idx);
    float4 a = src[0], b = src[1];
    bf16x8 o;
    o[0] = (bf16_t)a.x; o[1] = (bf16_t)a.y; o[2] = (bf16_t)a.z; o[3] = (bf16_t)a.w;
    o[4] = (bf16_t)b.x; o[5] = (bf16_t)b.y; o[6] = (bf16_t)b.z; o[7] = (bf16_t)b.w;
    *reinterpret_cast<bf16x8*>(zb + idx) = o;
}

// --- pack W1 [384,128] f32 row-major -> MFMA B-fragment order bf16 ----------
// frag index f = (kstep*8 + ntile); element j of lane l:
//   B[k = kstep*32 + (l>>4)*8 + j][n = ntile*16 + (l&15)]
__global__ void pack_w1_kernel(const float* __restrict__ W1, bf16_t* __restrict__ Wp) {
    int f = blockIdx.x * 256 + threadIdx.x;     // 0 .. 12*8*64-1
    if (f >= N_KSTEP * N_NTILE * 64) return;
    int lane = f & 63;
    int nt   = (f >> 6) & 7;
    int ks   = f >> 9;
    int n  = nt * 16 + (lane & 15);
    int k0 = ks * 32 + (lane >> 4) * 8;
    bf16x8 o;
#pragma unroll
    for (int j = 0; j < 8; ++j) o[j] = (bf16_t)W1[(k0 + j) * DIM + n];
    reinterpret_cast<bf16x8*>(Wp)[f] = o;
}

// --- main fused kernel ------------------------------------------------------
template <bool PRECAST>
__global__ __launch_bounds__(512, 1)
void decode_kernel(const void* __restrict__ zsrc,
                   const int* __restrict__ ei,       // [2*E]
                   const bf16_t* __restrict__ Wp,    // packed W1 (96KB)
                   const float* __restrict__ b1,
                   const float* __restrict__ W2,
                   const float* __restrict__ b2,
                   float* __restrict__ out, int E) {
    __shared__ __align__(16) bf16_t Bsm[N_KSTEP * N_NTILE * 64 * 8];  // 96 KiB

    const int tid = threadIdx.x;

    // ---- stage packed W1 into LDS, once per persistent block ----
    {
        const uint4* src = reinterpret_cast<const uint4*>(Wp);
        uint4* dst = reinterpret_cast<uint4*>(Bsm);
#pragma unroll
        for (int i = 0; i < 12; ++i)            // 12 * 512 * 16B = 96 KiB
            dst[i * 512 + tid] = src[i * 512 + tid];
    }
    __syncthreads();    // the only block-wide barrier in the kernel

    const int wave = tid >> 6, lane = tid & 63;
    const int l15 = lane & 15, quad = lane >> 4;
    const float bias2 = b2[0];

    // ---- epilogue params (full n range per wave) ----
    float b1v[8], w2v[8];
#pragma unroll
    for (int nt = 0; nt < 8; ++nt) {
        int n = nt * 16 + l15;
        b1v[nt] = b1[n];
        w2v[nt] = W2[n];
    }

    const int ntiles = (E + E_TILE - 1) / E_TILE;

    // gather one 16B chunk of zu/zv for (mt, c): cols [c*32+quad*8, +8)
    auto gatherChunk = [&](bf16x8& du, bf16x8& dv, int nu, int nv, int c) {
        if (PRECAST) {
            const bf16_t* zb = (const bf16_t*)zsrc;
            du = *reinterpret_cast<const bf16x8*>(zb + (size_t)nu * DIM + c * 32 + quad * 8);
            dv = *reinterpret_cast<const bf16x8*>(zb + (size_t)nv * DIM + c * 32 + quad * 8);
        } else {
            const float* zf = (const float*)zsrc;
            const float4* pu = reinterpret_cast<const float4*>(zf + (size_t)nu * DIM + c * 32 + quad * 8);
            const float4* pv = reinterpret_cast<const float4*>(zf + (size_t)nv * DIM + c * 32 + quad * 8);
            float4 a = pu[0], b = pu[1];
            bf16x8 o;
            o[0] = (bf16_t)a.x; o[1] = (bf16_t)a.y; o[2] = (bf16_t)a.z; o[3] = (bf16_t)a.w;
            o[4] = (bf16_t)b.x; o[5] = (bf16_t)b.y; o[6] = (bf16_t)b.z; o[7] = (bf16_t)b.w;
            du = o;
            a = pv[0]; b = pv[1];
            o[0] = (bf16_t)a.x; o[1] = (bf16_t)a.y; o[2] = (bf16_t)a.z; o[3] = (bf16_t)a.w;
            o[4] = (bf16_t)b.x; o[5] = (bf16_t)b.y; o[6] = (bf16_t)b.z; o[7] = (bf16_t)b.w;
            dv = o;
        }
    };

    // load the 4 B-frags of n-half h for kstep ks
    auto loadB4 = [&](bf16x8* dst, int ks, int h) {
#pragma unroll
        for (int nt = 0; nt < 4; ++nt)
            dst[nt] = *reinterpret_cast<const bf16x8*>(
                &Bsm[(size_t)((ks * N_NTILE + h * 4 + nt) * 64 + lane) * 8]);
    };

    // ---- A-chunk ping-pong (2 chunks live at a time, 32 arch regs) ----
    struct AChunk { bf16x8 u[2], v[2]; };
    AChunk A0, A1;
    int cnu[2], cnv[2], nnu[2], nnv[2];

    auto loadIdx = [&](int t, int mt, int& nu, int& nv) {
        int e = t * E_TILE + wave * 32 + mt * 16 + l15;
        if (e >= E) e = E - 1;                   // clamp: harmless duplicate work
        nu = ei[e];
        nv = ei[E + e];
    };

    // prologue: indices + chunk 0 of the first tile
#pragma unroll
    for (int mt = 0; mt < 2; ++mt) loadIdx(blockIdx.x, mt, cnu[mt], cnv[mt]);
#pragma unroll
    for (int mt = 0; mt < 2; ++mt)
        gatherChunk(A0.u[mt], A0.v[mt], cnu[mt], cnv[mt], 0);

    // ---- persistent grid-stride loop ----
    for (int t = blockIdx.x; t < ntiles; t += GRID_B) {
        // next tile's node indices (needed by the g=3 prefetch)
#pragma unroll
        for (int mt = 0; mt < 2; ++mt) loadIdx(t + GRID_B, mt, nnu[mt], nnv[mt]);

        floatx4 acc[2][8];
#pragma unroll
        for (int mt = 0; mt < 2; ++mt)
#pragma unroll
            for (int nt = 0; nt < 8; ++nt) acc[mt][nt] = (floatx4)0.0f;

        // 4 c-groups; group g computes ks {g, 4+g, 8+g} from CUR while
        // prefetching chunk g+1 (or next tile's chunk 0) into NXT.
#pragma unroll
        for (int g = 0; g < 4; ++g) {
            AChunk& cur = (g & 1) ? A1 : A0;
            AChunk& nxt = (g & 1) ? A0 : A1;

            // issue prefetch first; result not needed until group g+1
            if (g < 3) {
#pragma unroll
                for (int mt = 0; mt < 2; ++mt)
                    gatherChunk(nxt.u[mt], nxt.v[mt], cnu[mt], cnv[mt], g + 1);
            } else {
#pragma unroll
                for (int mt = 0; mt < 2; ++mt)
                    gatherChunk(nxt.u[mt], nxt.v[mt], nnu[mt], nnv[mt], 0);
            }

            {   // ks = g : A = zu chunk g
#pragma unroll
                for (int h = 0; h < 2; ++h) {
                    bf16x8 bc[4];
                    loadB4(bc, g, h);
#pragma unroll
                    for (int mt = 0; mt < 2; ++mt)
#pragma unroll
                        for (int nt = 0; nt < 4; ++nt)
                            acc[mt][h * 4 + nt] = __builtin_amdgcn_mfma_f32_16x16x32_bf16(
                                cur.u[mt], bc[nt], acc[mt][h * 4 + nt], 0, 0, 0);
                }
            }
            {   // ks = 4+g : A = zv chunk g
#pragma unroll
                for (int h = 0; h < 2; ++h) {
                    bf16x8 bc[4];
                    loadB4(bc, 4 + g, h);
#pragma unroll
                    for (int mt = 0; mt < 2; ++mt)
#pragma unroll
                        for (int nt = 0; nt < 4; ++nt)
                            acc[mt][h * 4 + nt] = __builtin_amdgcn_mfma_f32_16x16x32_bf16(
                                cur.v[mt], bc[nt], acc[mt][h * 4 + nt], 0, 0, 0);
                }
            }
            {   // ks = 8+g : A = |zu - zv| chunk g
                bf16x8 d[2];
#pragma unroll
                for (int mt = 0; mt < 2; ++mt) {
                    bf16x8 u = cur.u[mt], v = cur.v[mt];
#pragma unroll
                    for (int j = 0; j < 8; ++j)
                        d[mt][j] = (bf16_t)fabsf((float)u[j] - (float)v[j]);
                }
#pragma unroll
                for (int h = 0; h < 2; ++h) {
                    bf16x8 bc[4];
                    loadB4(bc, 8 + g, h);
#pragma unroll
                    for (int mt = 0; mt < 2; ++mt)
#pragma unroll
                        for (int nt = 0; nt < 4; ++nt)
                            acc[mt][h * 4 + nt] = __builtin_amdgcn_mfma_f32_16x16x32_bf16(
                                d[mt], bc[nt], acc[mt][h * 4 + nt], 0, 0, 0);
                }
            }
        }
        // after g=3: A0 holds chunk 0 of tile t+GRID_B
#pragma unroll
        for (int mt = 0; mt < 2; ++mt) { cnu[mt] = nnu[mt]; cnv[mt] = nnv[mt]; }

        // ---- epilogue: bias + relu + dot(W2), in-wave butterfly over n ----
        // C/D layout: n = nt*16 + l15, m = quad*4 + r
#pragma unroll
        for (int mt = 0; mt < 2; ++mt)
#pragma unroll
            for (int r = 0; r < 4; ++r) {
                float s = 0.f;
#pragma unroll
                for (int nt = 0; nt < 8; ++nt) {
                    float hh = acc[mt][nt][r] + b1v[nt];
                    hh = fmaxf(hh, 0.f);
                    s += hh * w2v[nt];
                }
                s += __shfl_xor(s, 1);
                s += __shfl_xor(s, 2);
                s += __shfl_xor(s, 4);
                s += __shfl_xor(s, 8);
                if (l15 == 0) {
                    int e = t * E_TILE + wave * 32 + mt * 16 + quad * 4 + r;
                    if (e < E) out[e] = s + bias2;
                }
            }
    }
}

// ---------------------------------------------------------------------------
extern "C" void kernel_launch(void* const* d_in, const int* in_sizes, int n_in,
                              void* d_out, int out_size, void* d_ws, size_t ws_size,
                              hipStream_t stream) {
    const float* z  = (const float*)d_in[0];
    const int*   ei = (const int*)d_in[1];
    const float* W1 = (const float*)d_in[2];
    const float* b1 = (const float*)d_in[3];
    const float* W2 = (const float*)d_in[4];
    const float* b2 = (const float*)d_in[5];
    float* out = (float*)d_out;

    const int E  = in_sizes[1] / 2;
    const int zn = in_sizes[0];

    const size_t zb_bytes = (size_t)zn * sizeof(bf16_t);
    const size_t wp_bytes = (size_t)N_KSTEP * N_NTILE * 64 * 16;  // 98304
    const bool precast = ws_size >= zb_bytes + wp_bytes;

    bf16_t* zb = (bf16_t*)d_ws;
    bf16_t* wp = precast ? (bf16_t*)((char*)d_ws + zb_bytes) : (bf16_t*)d_ws;

    hipLaunchKernelGGL(pack_w1_kernel, dim3((N_KSTEP * N_NTILE * 64 + 255) / 256),
                       dim3(256), 0, stream, W1, wp);

    if (precast) {
        hipLaunchKernelGGL(cast_z_kernel, dim3((zn / 8 + 255) / 256), dim3(256),
                           0, stream, z, zb, zn);
        hipLaunchKernelGGL((decode_kernel<true>), dim3(GRID_B), dim3(512), 0,
                           stream, (const void*)zb, ei, wp, b1, W2, b2, out, E);
    } else {
        hipLaunchKernelGGL((decode_kernel<false>), dim3(GRID_B), dim3(512), 0,
                           stream, (const void*)z, ei, wp, b1, W2, b2, out, E);
    }
}

// Round 7
// 194.080 us; speedup vs baseline: 2.1410x; 2.0462x over previous
//
#include <hip/hip_runtime.h>
#include <hip/hip_bf16.h>
#include <cstdint>

// ---------------------------------------------------------------------------
// MLPDecoder: logit[e] = relu([zu, zv, |zu-zv|] @ W1 + b1) @ W2 + b2
//   z: [100000,128] f32, edge_index: [2,E] int, W1: [384,128], b1:[128],
//   W2: [128,1], b2:[1].  Output: [E] f32.
//
// R7: R6's persistent W1-in-LDS structure + R1's PROVEN-lean wave geometry.
//   Evidence: R3/R4/R6 all spilled ~45 dwords/thread/tile (WRITE_SIZE 182-190
//   MB) regardless of A-state size => the acc[2][8]=64 accumulator itself
//   doesn't stay resident at 8-wave blocks. R1 (acc[2][4]=32, wn-split)
//   compiled to VGPR=68 with zero spill. So: 8 waves = 4 wm x 2 wn, each wave
//   32 edges x 64 n-cols. acc 32, B-transients 16, A ping-pong 32.
//  - 256 persistent blocks x 512 threads (1 block/CU), W1 96KB in LDS.
//  - K-loop c-groups (ks = g,4+g,8+g); chunk g dies after its |u-v| MFMA;
//    chunk g+1 (or next tile's chunk 0) prefetched into the other ping-pong
//    buffer during group g.
//  - Cross-wn reduce via parity-buffered LDS (ONE barrier per tile).
// ---------------------------------------------------------------------------

typedef __bf16 bf16_t;
typedef __bf16 bf16x8 __attribute__((ext_vector_type(8)));
typedef float  floatx4 __attribute__((ext_vector_type(4)));

#define DIM 128
#define E_TILE 128          // edges per block-tile (4 wm-groups x 32 edges)
#define N_KSTEP 12          // 384 / 32
#define N_NTILE 8           // 128 / 16
#define GRID_B 256          // persistent blocks (1 per CU)

// --- cast z fp32 -> bf16 ----------------------------------------------------
__global__ void cast_z_kernel(const float* __restrict__ z, bf16_t* __restrict__ zb, int n) {
    int idx = (blockIdx.x * 256 + threadIdx.x) * 8;
    if (idx + 8 > n) return;
    const float4* src = reinterpret_cast<const float4*>(z + idx);
    float4 a = src[0], b = src[1];
    bf16x8 o;
    o[0] = (bf16_t)a.x; o[1] = (bf16_t)a.y; o[2] = (bf16_t)a.z; o[3] = (bf16_t)a.w;
    o[4] = (bf16_t)b.x; o[5] = (bf16_t)b.y; o[6] = (bf16_t)b.z; o[7] = (bf16_t)b.w;
    *reinterpret_cast<bf16x8*>(zb + idx) = o;
}

// --- pack W1 [384,128] f32 row-major -> MFMA B-fragment order bf16 ----------
// frag index f = (kstep*8 + ntile); element j of lane l:
//   B[k = kstep*32 + (l>>4)*8 + j][n = ntile*16 + (l&15)]
__global__ void pack_w1_kernel(const float* __restrict__ W1, bf16_t* __restrict__ Wp) {
    int f = blockIdx.x * 256 + threadIdx.x;     // 0 .. 12*8*64-1
    if (f >= N_KSTEP * N_NTILE * 64) return;
    int lane = f & 63;
    int nt   = (f >> 6) & 7;
    int ks   = f >> 9;
    int n  = nt * 16 + (lane & 15);
    int k0 = ks * 32 + (lane >> 4) * 8;
    bf16x8 o;
#pragma unroll
    for (int j = 0; j < 8; ++j) o[j] = (bf16_t)W1[(k0 + j) * DIM + n];
    reinterpret_cast<bf16x8*>(Wp)[f] = o;
}

// --- main fused kernel ------------------------------------------------------
template <bool PRECAST>
__global__ __launch_bounds__(512, 2)
void decode_kernel(const void* __restrict__ zsrc,
                   const int* __restrict__ ei,       // [2*E]
                   const bf16_t* __restrict__ Wp,    // packed W1 (96KB)
                   const float* __restrict__ b1,
                   const float* __restrict__ W2,
                   const float* __restrict__ b2,
                   float* __restrict__ out, int E) {
    __shared__ __align__(16) bf16_t Bsm[N_KSTEP * N_NTILE * 64 * 8];  // 96 KiB
    __shared__ float red[2][2][E_TILE];                               // 2 KiB

    const int tid = threadIdx.x;

    // ---- stage packed W1 into LDS, once per persistent block ----
    {
        const uint4* src = reinterpret_cast<const uint4*>(Wp);
        uint4* dst = reinterpret_cast<uint4*>(Bsm);
#pragma unroll
        for (int i = 0; i < 12; ++i)            // 12 * 512 * 16B = 96 KiB
            dst[i * 512 + tid] = src[i * 512 + tid];
    }
    __syncthreads();

    const int wave = tid >> 6, lane = tid & 63;
    const int wm = wave >> 1, wn = wave & 1;    // 4 wm x 2 wn
    const int l15 = lane & 15, quad = lane >> 4;
    const float bias2 = b2[0];

    // ---- epilogue params (this wave's n-half) ----
    float b1v[4], w2v[4];
#pragma unroll
    for (int nt = 0; nt < 4; ++nt) {
        int n = (wn * 4 + nt) * 16 + l15;
        b1v[nt] = b1[n];
        w2v[nt] = W2[n];
    }

    const int ntiles = (E + E_TILE - 1) / E_TILE;

    // gather one 16B chunk of zu/zv for (mt, c): cols [c*32+quad*8, +8)
    auto gatherChunk = [&](bf16x8& du, bf16x8& dv, int nu, int nv, int c) {
        if (PRECAST) {
            const bf16_t* zb = (const bf16_t*)zsrc;
            du = *reinterpret_cast<const bf16x8*>(zb + (size_t)nu * DIM + c * 32 + quad * 8);
            dv = *reinterpret_cast<const bf16x8*>(zb + (size_t)nv * DIM + c * 32 + quad * 8);
        } else {
            const float* zf = (const float*)zsrc;
            const float4* pu = reinterpret_cast<const float4*>(zf + (size_t)nu * DIM + c * 32 + quad * 8);
            const float4* pv = reinterpret_cast<const float4*>(zf + (size_t)nv * DIM + c * 32 + quad * 8);
            float4 a = pu[0], b = pu[1];
            bf16x8 o;
            o[0] = (bf16_t)a.x; o[1] = (bf16_t)a.y; o[2] = (bf16_t)a.z; o[3] = (bf16_t)a.w;
            o[4] = (bf16_t)b.x; o[5] = (bf16_t)b.y; o[6] = (bf16_t)b.z; o[7] = (bf16_t)b.w;
            du = o;
            a = pv[0]; b = pv[1];
            o[0] = (bf16_t)a.x; o[1] = (bf16_t)a.y; o[2] = (bf16_t)a.z; o[3] = (bf16_t)a.w;
            o[4] = (bf16_t)b.x; o[5] = (bf16_t)b.y; o[6] = (bf16_t)b.z; o[7] = (bf16_t)b.w;
            dv = o;
        }
    };

    // load the 4 B-frags of this wave's n-half for kstep ks
    auto loadB4 = [&](bf16x8* dst, int ks) {
#pragma unroll
        for (int nt = 0; nt < 4; ++nt)
            dst[nt] = *reinterpret_cast<const bf16x8*>(
                &Bsm[(size_t)((ks * N_NTILE + wn * 4 + nt) * 64 + lane) * 8]);
    };

    auto loadIdx = [&](int t, int mt, int& nu, int& nv) {
        int e = t * E_TILE + wm * 32 + mt * 16 + l15;
        if (e >= E) e = E - 1;                   // clamp: harmless duplicate work
        nu = ei[e];
        nv = ei[E + e];
    };

    // ---- A-chunk ping-pong (2 chunks live at a time, 32 arch regs) ----
    struct AChunk { bf16x8 u[2], v[2]; };
    AChunk A0, A1;
    int cnu[2], cnv[2], nnu[2], nnv[2];

    // prologue: indices + chunk 0 of the first tile
#pragma unroll
    for (int mt = 0; mt < 2; ++mt) loadIdx(blockIdx.x, mt, cnu[mt], cnv[mt]);
#pragma unroll
    for (int mt = 0; mt < 2; ++mt)
        gatherChunk(A0.u[mt], A0.v[mt], cnu[mt], cnv[mt], 0);

    int p = 0;  // red parity

    // ---- persistent grid-stride loop ----
    for (int t = blockIdx.x; t < ntiles; t += GRID_B) {
        // next tile's node indices (needed by the g=3 prefetch)
#pragma unroll
        for (int mt = 0; mt < 2; ++mt) loadIdx(t + GRID_B, mt, nnu[mt], nnv[mt]);

        floatx4 acc[2][4];
#pragma unroll
        for (int mt = 0; mt < 2; ++mt)
#pragma unroll
            for (int nt = 0; nt < 4; ++nt) acc[mt][nt] = (floatx4)0.0f;

        // 4 c-groups; group g computes ks {g, 4+g, 8+g} from CUR while
        // prefetching chunk g+1 (or next tile's chunk 0) into NXT.
#pragma unroll
        for (int g = 0; g < 4; ++g) {
            AChunk& cur = (g & 1) ? A1 : A0;
            AChunk& nxt = (g & 1) ? A0 : A1;

            // issue prefetch first; result not needed until group g+1
            if (g < 3) {
#pragma unroll
                for (int mt = 0; mt < 2; ++mt)
                    gatherChunk(nxt.u[mt], nxt.v[mt], cnu[mt], cnv[mt], g + 1);
            } else {
#pragma unroll
                for (int mt = 0; mt < 2; ++mt)
                    gatherChunk(nxt.u[mt], nxt.v[mt], nnu[mt], nnv[mt], 0);
            }

            {   // ks = g : A = zu chunk g
                bf16x8 bc[4];
                loadB4(bc, g);
#pragma unroll
                for (int mt = 0; mt < 2; ++mt)
#pragma unroll
                    for (int nt = 0; nt < 4; ++nt)
                        acc[mt][nt] = __builtin_amdgcn_mfma_f32_16x16x32_bf16(
                            cur.u[mt], bc[nt], acc[mt][nt], 0, 0, 0);
            }
            {   // ks = 4+g : A = zv chunk g
                bf16x8 bc[4];
                loadB4(bc, 4 + g);
#pragma unroll
                for (int mt = 0; mt < 2; ++mt)
#pragma unroll
                    for (int nt = 0; nt < 4; ++nt)
                        acc[mt][nt] = __builtin_amdgcn_mfma_f32_16x16x32_bf16(
                            cur.v[mt], bc[nt], acc[mt][nt], 0, 0, 0);
            }
            {   // ks = 8+g : A = |zu - zv| chunk g
                bf16x8 bc[4];
                loadB4(bc, 8 + g);
#pragma unroll
                for (int mt = 0; mt < 2; ++mt) {
                    bf16x8 u = cur.u[mt], v = cur.v[mt];
                    bf16x8 d;
#pragma unroll
                    for (int j = 0; j < 8; ++j)
                        d[j] = (bf16_t)fabsf((float)u[j] - (float)v[j]);
#pragma unroll
                    for (int nt = 0; nt < 4; ++nt)
                        acc[mt][nt] = __builtin_amdgcn_mfma_f32_16x16x32_bf16(
                            d, bc[nt], acc[mt][nt], 0, 0, 0);
                }
            }
        }
        // after g=3: A0 holds chunk 0 of tile t+GRID_B
#pragma unroll
        for (int mt = 0; mt < 2; ++mt) { cnu[mt] = nnu[mt]; cnv[mt] = nnv[mt]; }

        // ---- epilogue: bias + relu + dot(W2-half), butterfly over 16 lanes ----
        // C/D layout: n = (wn*4+nt)*16 + l15, m = quad*4 + r
#pragma unroll
        for (int mt = 0; mt < 2; ++mt)
#pragma unroll
            for (int r = 0; r < 4; ++r) {
                float s = 0.f;
#pragma unroll
                for (int nt = 0; nt < 4; ++nt) {
                    float hh = acc[mt][nt][r] + b1v[nt];
                    hh = fmaxf(hh, 0.f);
                    s += hh * w2v[nt];
                }
                s += __shfl_xor(s, 1);
                s += __shfl_xor(s, 2);
                s += __shfl_xor(s, 4);
                s += __shfl_xor(s, 8);
                if (l15 == 0)
                    red[p][wn][wm * 32 + mt * 16 + quad * 4 + r] = s;
            }
        __syncthreads();    // one barrier per tile (parity buffer allows it)

        if (tid < E_TILE) {
            int e = t * E_TILE + tid;
            if (e < E) out[e] = red[p][0][tid] + red[p][1][tid] + bias2;
        }
        p ^= 1;
    }
}

// ---------------------------------------------------------------------------
extern "C" void kernel_launch(void* const* d_in, const int* in_sizes, int n_in,
                              void* d_out, int out_size, void* d_ws, size_t ws_size,
                              hipStream_t stream) {
    const float* z  = (const float*)d_in[0];
    const int*   ei = (const int*)d_in[1];
    const float* W1 = (const float*)d_in[2];
    const float* b1 = (const float*)d_in[3];
    const float* W2 = (const float*)d_in[4];
    const float* b2 = (const float*)d_in[5];
    float* out = (float*)d_out;

    const int E  = in_sizes[1] / 2;
    const int zn = in_sizes[0];

    const size_t zb_bytes = (size_t)zn * sizeof(bf16_t);
    const size_t wp_bytes = (size_t)N_KSTEP * N_NTILE * 64 * 16;  // 98304
    const bool precast = ws_size >= zb_bytes + wp_bytes;

    bf16_t* zb = (bf16_t*)d_ws;
    bf16_t* wp = precast ? (bf16_t*)((char*)d_ws + zb_bytes) : (bf16_t*)d_ws;

    hipLaunchKernelGGL(pack_w1_kernel, dim3((N_KSTEP * N_NTILE * 64 + 255) / 256),
                       dim3(256), 0, stream, W1, wp);

    if (precast) {
        hipLaunchKernelGGL(cast_z_kernel, dim3((zn / 8 + 255) / 256), dim3(256),
                           0, stream, z, zb, zn);
        hipLaunchKernelGGL((decode_kernel<true>), dim3(GRID_B), dim3(512), 0,
                           stream, (const void*)zb, ei, wp, b1, W2, b2, out, E);
    } else {
        hipLaunchKernelGGL((decode_kernel<false>), dim3(GRID_B), dim3(512), 0,
                           stream, (const void*)z, ei, wp, b1, W2, b2, out, E);
    }
}